// Round 2
// baseline (326.972 us; speedup 1.0000x reference)
//
#include <hip/hip_runtime.h>

#define DT 0.001f
#define TAU_SYN_INV 200.0f
#define V_TH 1.0f

// Native vector type — __builtin_nontemporal_* requires a true vector, not
// HIP's struct-based float4.
typedef float vfloat4 __attribute__((ext_vector_type(4)));

// B,C,H,W = 16,64,128,128 ; N = 16777216 ; HW = 16384 elems = 4096 float4
#define EPT 2

__device__ __forceinline__ void lif_step(const vfloat4 v, const vfloat4 c,
                                         const vfloat4 xx, const float dt_tau,
                                         vfloat4& z, vfloat4& vn, vfloat4& in_)
{
    const float isyn_decay = 1.0f - DT * TAU_SYN_INV;   // 0.8
    #pragma unroll
    for (int k = 0; k < 4; ++k) {
        float vd = fmaf(dt_tau, c[k] - v[k], v[k]);
        bool s = vd > V_TH;
        z[k]   = s ? 1.0f : 0.0f;
        vn[k]  = s ? 0.0f : vd;
        in_[k] = fmaf(isyn_decay, c[k], xx[k]);
    }
}

__global__ __launch_bounds__(256) void trf_kernel(
    const vfloat4* __restrict__ x,
    const vfloat4* __restrict__ v0,
    const vfloat4* __restrict__ icur,
    const float*   __restrict__ ps,
    vfloat4* __restrict__ out_z,
    vfloat4* __restrict__ out_v,
    vfloat4* __restrict__ out_i,
    int n4)
{
    const int tid    = blockIdx.x * blockDim.x + threadIdx.x;
    const int stride = gridDim.x * blockDim.x;
    const int ia = tid;
    const int ib = tid + stride;

    if (ib < n4) {
        // Fast path (always taken at this shape): issue ALL SIX loads before
        // any compute/store — 6 loads in flight per thread, no control-flow
        // edge between the two halves, so no mid-body vmcnt(0) drain.
        const vfloat4 va = __builtin_nontemporal_load(&v0[ia]);
        const vfloat4 ca = __builtin_nontemporal_load(&icur[ia]);
        const vfloat4 xa = __builtin_nontemporal_load(&x[ia]);
        const vfloat4 vb = __builtin_nontemporal_load(&v0[ib]);
        const vfloat4 cb = __builtin_nontemporal_load(&icur[ib]);
        const vfloat4 xb = __builtin_nontemporal_load(&x[ib]);

        // channel = (elem / (H*W)) % C = (i4 / 4096) % 64 — wave-uniform
        const float dta = DT * ps[(ia >> 12) & 63];
        const float dtb = DT * ps[(ib >> 12) & 63];

        vfloat4 za, vna, ina, zb, vnb, inb;
        lif_step(va, ca, xa, dta, za, vna, ina);
        lif_step(vb, cb, xb, dtb, zb, vnb, inb);

        __builtin_nontemporal_store(za,  &out_z[ia]);
        __builtin_nontemporal_store(vna, &out_v[ia]);
        __builtin_nontemporal_store(ina, &out_i[ia]);
        __builtin_nontemporal_store(zb,  &out_z[ib]);
        __builtin_nontemporal_store(vnb, &out_v[ib]);
        __builtin_nontemporal_store(inb, &out_i[ib]);
    } else if (ia < n4) {
        // Tail (never taken when grid*block*EPT == n4 exactly)
        const vfloat4 va = __builtin_nontemporal_load(&v0[ia]);
        const vfloat4 ca = __builtin_nontemporal_load(&icur[ia]);
        const vfloat4 xa = __builtin_nontemporal_load(&x[ia]);
        const float dta = DT * ps[(ia >> 12) & 63];

        vfloat4 za, vna, ina;
        lif_step(va, ca, xa, dta, za, vna, ina);

        __builtin_nontemporal_store(za,  &out_z[ia]);
        __builtin_nontemporal_store(vna, &out_v[ia]);
        __builtin_nontemporal_store(ina, &out_i[ia]);
    }
}

extern "C" void kernel_launch(void* const* d_in, const int* in_sizes, int n_in,
                              void* d_out, int out_size, void* d_ws, size_t ws_size,
                              hipStream_t stream) {
    const float* x  = (const float*)d_in[0];
    const float* v0 = (const float*)d_in[1];
    const float* i0 = (const float*)d_in[2];
    const float* ps = (const float*)d_in[3];

    const int N  = in_sizes[0];          // 16777216
    const int n4 = N / 4;                // 4194304

    float* out = (float*)d_out;
    vfloat4* out_z = (vfloat4*)out;
    vfloat4* out_v = (vfloat4*)(out + (size_t)N);
    vfloat4* out_i = (vfloat4*)(out + 2 * (size_t)N);

    const int block = 256;
    const int grid  = (n4 + block * EPT - 1) / (block * EPT);  // 8192 blocks

    trf_kernel<<<grid, block, 0, stream>>>(
        (const vfloat4*)x, (const vfloat4*)v0, (const vfloat4*)i0, ps,
        out_z, out_v, out_i, n4);
}